// Round 5
// baseline (497.499 us; speedup 1.0000x reference)
//
#include <hip/hip_runtime.h>
#include <hip/hip_bf16.h>

#define IN_F   1024
#define OUT_F  1024
#define NBASIS 8
#define KDIM   (IN_F + IN_F * NBASIS)   // 9216
#define BK 64
#define KT      (KDIM / BK)             // 144

// ---- k_gemm5 geometry ----------------------------------------------------
#define BM3 128
#define BN3 256
#define B_ELEMS (BN3 * BK)              // 16384 shorts (32 KB)

// ---- fallback geometry ----------------------------------------------------
#define BM 128
#define BN 128

typedef __attribute__((ext_vector_type(8)))  short          bf16x8;
typedef __attribute__((ext_vector_type(8)))  unsigned short u16x8;
typedef __attribute__((ext_vector_type(4)))  float          f32x4;

typedef const __attribute__((address_space(1))) void gas_t;
typedef __attribute__((address_space(3))) void las_t;
#define GLD16(g, l) __builtin_amdgcn_global_load_lds((gas_t*)(g), (las_t*)(l), 16, 0, 0)

// ---- helpers -------------------------------------------------------------
__device__ __forceinline__ unsigned short bfr(float f) {
    unsigned u = __float_as_uint(f);
    unsigned r = (u + 0x7FFFu + ((u >> 16) & 1u)) >> 16;
    return (unsigned short)r;
}
__device__ __forceinline__ float silu_f(float v) { return v / (1.0f + __expf(-v)); }

__device__ __forceinline__ unsigned fkey(float f) {
    unsigned u = __float_as_uint(f);
    return u ^ ((u >> 31) ? 0xFFFFFFFFu : 0x80000000u);
}
__device__ __forceinline__ float fkey_dec(unsigned u) {
    unsigned b = (u >> 31) ? (u ^ 0x80000000u) : ~u;
    return __uint_as_float(b);
}

// spline basis (uniform cubic, closed form — validated rounds 1-4)
__device__ __forceinline__ void spline8(float xv, float xmin, float scale, u16x8* o8p) {
    float xn = (xv - xmin) * scale - 1.0f;
    float u  = (xn + 2.2f) * 2.5f;       // h=0.4, t0=-2.2
    int   iv = (int)floorf(u);
    iv = iv < 3 ? 3 : (iv > 7 ? 7 : iv);
    float tt = u - (float)iv;
    float s1 = 1.0f - tt;
    float t2 = tt * tt, t3 = t2 * tt;
    float n0 = s1 * s1 * s1 * (1.0f / 6.0f);
    float n1 = (3.0f * t3 - 6.0f * t2 + 4.0f) * (1.0f / 6.0f);
    float n2 = (-3.0f * t3 + 3.0f * t2 + 3.0f * tt + 1.0f) * (1.0f / 6.0f);
    float n3 = t3 * (1.0f / 6.0f);
    int j0 = iv - 3;
    u16x8 o8;
    #pragma unroll
    for (int s = 0; s < 8; ++s) {
        int d = s - j0;
        float val = (d == 0) ? n0 : (d == 1) ? n1 : (d == 2) ? n2 : (d == 3) ? n3 : 0.0f;
        o8[s] = bfr(val);
    }
    *o8p = o8;
}

// ---- kernel 1: global min/max of x --------------------------------------
__global__ void k_minmax(const float* __restrict__ x, unsigned* __restrict__ mm, int n4) {
    int tid    = blockIdx.x * blockDim.x + threadIdx.x;
    int stride = gridDim.x * blockDim.x;
    const float4* x4 = (const float4*)x;
    float mx  = -3.402823466e+38f;
    float mxn = -3.402823466e+38f;
    for (int i = tid; i < n4; i += stride) {
        float4 v = x4[i];
        mx  = fmaxf(mx,  fmaxf(fmaxf(v.x, v.y), fmaxf(v.z, v.w)));
        mxn = fmaxf(mxn, -fminf(fminf(v.x, v.y), fminf(v.z, v.w)));
    }
    #pragma unroll
    for (int off = 32; off; off >>= 1) {
        mx  = fmaxf(mx,  __shfl_down(mx,  off));
        mxn = fmaxf(mxn, __shfl_down(mxn, off));
    }
    __shared__ float smx[4], smn[4];
    int lane = threadIdx.x & 63, wid = threadIdx.x >> 6;
    if (lane == 0) { smx[wid] = mx; smn[wid] = mxn; }
    __syncthreads();
    if (threadIdx.x == 0) {
        #pragma unroll
        for (int w = 1; w < 4; ++w) { mx = fmaxf(mx, smx[w]); mxn = fmaxf(mxn, smn[w]); }
        atomicMax(&mm[0], fkey(mx));
        atomicMax(&mm[1], fkey(mxn));
    }
}

// ---- kernel 2: merged prep — build Ac AND Wc in one launch ---------------
__global__ void k_prep_all(const float* __restrict__ x, const unsigned* __restrict__ mm,
                           const float* __restrict__ bw, const float* __restrict__ sw,
                           const float* __restrict__ sc,
                           unsigned short* __restrict__ Ac, unsigned short* __restrict__ Wc,
                           int nba) {
    int bid = blockIdx.x;
    if (bid < nba) {
        int t = bid * 256 + threadIdx.x;
        int row = t >> 10, i = t & 1023;
        const float xmax  = fkey_dec(mm[0]);
        const float xmin  = -fkey_dec(mm[1]);
        const float scale = 2.0f / (xmax - xmin + 1e-8f);
        float xv = x[t];
        size_t rb = (size_t)row * KDIM;
        Ac[rb + i] = bfr(silu_f(xv));
        u16x8 o8;
        spline8(xv, xmin, scale, &o8);
        *(u16x8*)(Ac + rb + IN_F + (size_t)i * 8) = o8;
    } else {
        int t = (bid - nba) * 256 + threadIdx.x;
        int o = t >> 10, i = t & 1023;
        Wc[(size_t)o * KDIM + i] = bfr(bw[t]);
        float s = sc[t];
        const float4* swv = (const float4*)(sw + (size_t)t * 8);
        float4 a = swv[0], b = swv[1];
        u16x8 o8;
        o8[0] = bfr(a.x * s); o8[1] = bfr(a.y * s); o8[2] = bfr(a.z * s); o8[3] = bfr(a.w * s);
        o8[4] = bfr(b.x * s); o8[5] = bfr(b.y * s); o8[6] = bfr(b.z * s); o8[7] = bfr(b.w * s);
        *(u16x8*)(Wc + (size_t)o * KDIM + IN_F + i * 8) = o8;
    }
}

#define MFMA16(a, b, c) __builtin_amdgcn_mfma_f32_16x16x32_bf16((a), (b), (c), 0, 0, 0)

// ---- kernel 3: GEMM with A-operand direct from global to registers -------
// 128x256 tile, 8 waves (2M x 4N), wave tile 64x64, 16x16x32 MFMA.
// LDS = B only, triple-buffered (96 KB). One barrier + one vmcnt(12)/K-tile.
// Steady state in flight: [GLD B(t+2):4, A-loads(t+1):8] = 12.
// B ds_read pattern = round-3's measured-zero-conflict swizzle.
#define GEMM_BODY(AFC, AFN, KTCUR)                                              \
    {                                                                           \
        _Pragma("unroll")                                                       \
        for (int q = 0; q < 4; ++q) GLD16(pb[q], &Bs[o2 + (q * 8 + w) * 512]);  \
        _Pragma("unroll")                                                       \
        for (int q = 0; q < 4; ++q) pb[q] += BK;                                \
        if (++sk == KT) { sk = 0;                                               \
            _Pragma("unroll")                                                   \
            for (int q = 0; q < 4; ++q) pb[q] -= KDIM; }                        \
        int an = (KTCUR) + 1; if (an == KT) an = 0;                             \
        const unsigned short* ap = aBase + (size_t)an * BK;                     \
        _Pragma("unroll")                                                       \
        for (int mi = 0; mi < 4; ++mi) {                                        \
            AFN[mi][0] = *(const bf16x8*)(ap + mi * aMi);                       \
            AFN[mi][1] = *(const bf16x8*)(ap + mi * aMi + 32);                  \
        }                                                                       \
        bf16x8 bf[4][2];                                                        \
        _Pragma("unroll")                                                       \
        for (int ni = 0; ni < 4; ++ni) {                                        \
            int r = wcq * 64 + ni * 16 + l15;                                   \
            bf[ni][0] = *(const bf16x8*)&Bs[o0 + r * BK + ach0 * 8];            \
            bf[ni][1] = *(const bf16x8*)&Bs[o0 + r * BK + ach1 * 8];            \
        }                                                                       \
        __builtin_amdgcn_s_setprio(1);                                          \
        _Pragma("unroll")                                                       \
        for (int ni = 0; ni < 4; ++ni)                                          \
            _Pragma("unroll")                                                   \
            for (int mi = 0; mi < 4; ++mi) {                                    \
                acc[mi][ni] = MFMA16(AFC[mi][0], bf[ni][0], acc[mi][ni]);       \
                acc[mi][ni] = MFMA16(AFC[mi][1], bf[ni][1], acc[mi][ni]);       \
            }                                                                   \
        __builtin_amdgcn_s_setprio(0);                                          \
        asm volatile("s_waitcnt vmcnt(12)" ::: "memory");                       \
        asm volatile("s_barrier" ::: "memory");                                 \
        int _tmp = o0; o0 = o1; o1 = o2; o2 = _tmp;                             \
    }

__global__ __launch_bounds__(512, 2)
void k_gemm5(const unsigned short* __restrict__ Ac, const unsigned short* __restrict__ Wc,
             float* __restrict__ out) {
    __shared__ unsigned short Bs[3 * B_ELEMS];   // 96 KB

    const int t    = threadIdx.x;
    const int lane = t & 63, w = t >> 6;
    const int bid  = blockIdx.x;
    const int xcd = bid & 7, s = bid >> 3;
    const int bM  = xcd * 8 + (s & 7);        // [0,64)
    const int bN  = s >> 3;                   // [0,4)

    const int wave_r = w >> 2;                // M-half (64 rows)
    const int wcq    = w & 3;                 // N-quarter (64 cols)
    const int l15  = lane & 15;
    const int ach0 = (lane >> 4) ^ (lane & 7);
    const int ach1 = ach0 ^ 4;

    // B staging source pointers (chunk-XOR pre-swizzled global addrs)
    const unsigned short* pb[4];
    #pragma unroll
    for (int q = 0; q < 4; ++q) {
        int L = (q * 8 + w) * 64 + lane;
        int r = L >> 3, c = L & 7;
        pb[q] = Wc + (size_t)(bN * BN3 + r) * KDIM + (c ^ (r & 7)) * 8;
    }

    // A fragment base: row = bM*128 + wave_r*64 + l15, k-slot = (lane>>4)*8
    const unsigned short* aBase =
        Ac + (size_t)(bM * BM3 + wave_r * 64 + l15) * KDIM + (lane >> 4) * 8;
    const size_t aMi = (size_t)16 * KDIM;     // 16-row group stride

    f32x4 acc[4][4] = {};
    bf16x8 afA[4][2], afB[4][2];

    // ---- prologue: B(0)->slot0, B(1)->slot1, A(0)->afA ----
    #pragma unroll
    for (int q = 0; q < 4; ++q) GLD16(pb[q], &Bs[0 * B_ELEMS + (q * 8 + w) * 512]);
    #pragma unroll
    for (int q = 0; q < 4; ++q) GLD16(pb[q] + BK, &Bs[1 * B_ELEMS + (q * 8 + w) * 512]);
    #pragma unroll
    for (int mi = 0; mi < 4; ++mi) {
        afA[mi][0] = *(const bf16x8*)(aBase + mi * aMi);
        afA[mi][1] = *(const bf16x8*)(aBase + mi * aMi + 32);
    }
    #pragma unroll
    for (int q = 0; q < 4; ++q) pb[q] += 2 * BK;

    int o0 = 0, o1 = B_ELEMS, o2 = 2 * B_ELEMS;
    int sk = 2;

    asm volatile("s_waitcnt vmcnt(12)" ::: "memory");   // B(0) landed
    asm volatile("s_barrier" ::: "memory");

    for (int kt = 0; kt < KT; kt += 2) {
        GEMM_BODY(afA, afB, kt)
        GEMM_BODY(afB, afA, kt + 1)
    }

    // ---- epilogue: C/D layout col=lane&15, row=(lane>>4)*4+reg ----
    #pragma unroll
    for (int mi = 0; mi < 4; ++mi) {
        #pragma unroll
        for (int ni = 0; ni < 4; ++ni) {
            #pragma unroll
            for (int reg = 0; reg < 4; ++reg) {
                int row = bM * BM3 + wave_r * 64 + mi * 16 + (lane >> 4) * 4 + reg;
                int col = bN * BN3 + wcq * 64 + ni * 16 + l15;
                out[(size_t)row * OUT_F + col] = acc[mi][ni][reg];
            }
        }
    }
}

// ---- fallback GEMM (round-2 validated m97 structure, 16x16 MFMA) ---------
__global__ __launch_bounds__(256, 2)
void k_gemm2(const unsigned short* __restrict__ Ac, const unsigned short* __restrict__ Wc,
             float* __restrict__ out, int nmb) {
    __shared__ unsigned short As[BM * BK];
    __shared__ unsigned short Bs[BN * BK];

    const int t = threadIdx.x;
    const int lane = t & 63, w = t >> 6;
    int bid = blockIdx.x;
    int bM = bid >> 3, bN = bid & 7;

    const unsigned short* pa[4];
    const unsigned short* pb[4];
    #pragma unroll
    for (int q = 0; q < 4; ++q) {
        int idx = (q * 4 + w) * 64 + lane;
        int r = idx >> 3, c8 = idx & 7;
        pa[q] = Ac + (size_t)(bM * BM + r) * KDIM + c8 * 8;
        pb[q] = Wc + (size_t)(bN * BN + r) * KDIM + c8 * 8;
    }

    const int wr  = (w >> 1) * 64;
    const int wc2 = (w & 1) * 64;

    f32x4 acc[4][4] = {};

    for (int kt = 0; kt < KT; ++kt) {
        __syncthreads();
        #pragma unroll
        for (int q = 0; q < 4; ++q) {
            GLD16(pa[q], &As[(q * 4 + w) * 512]);
            GLD16(pb[q], &Bs[(q * 4 + w) * 512]);
            pa[q] += BK;
            pb[q] += BK;
        }
        __syncthreads();

        bf16x8 af[4][2];
        #pragma unroll
        for (int mi = 0; mi < 4; ++mi) {
            int row = wr + mi * 16 + (lane & 15);
            #pragma unroll
            for (int ks = 0; ks < 2; ++ks)
                af[mi][ks] = *(const bf16x8*)&As[row * BK + ks * 32 + (lane >> 4) * 8];
        }
        #pragma unroll
        for (int ni = 0; ni < 4; ++ni) {
            int col = wc2 + ni * 16 + (lane & 15);
            bf16x8 b0 = *(const bf16x8*)&Bs[col * BK + (lane >> 4) * 8];
            bf16x8 b1 = *(const bf16x8*)&Bs[col * BK + 32 + (lane >> 4) * 8];
            #pragma unroll
            for (int mi = 0; mi < 4; ++mi) {
                acc[mi][ni] = MFMA16(af[mi][0], b0, acc[mi][ni]);
                acc[mi][ni] = MFMA16(af[mi][1], b1, acc[mi][ni]);
            }
        }
    }

    #pragma unroll
    for (int mi = 0; mi < 4; ++mi) {
        #pragma unroll
        for (int ni = 0; ni < 4; ++ni) {
            #pragma unroll
            for (int reg = 0; reg < 4; ++reg) {
                int row = wr + mi * 16 + (lane >> 4) * 4 + reg;
                int col = wc2 + ni * 16 + (lane & 15);
                out[(size_t)(bM * BM + row) * OUT_F + bN * BN + col] = acc[mi][ni][reg];
            }
        }
    }
}

// ---- launch --------------------------------------------------------------
extern "C" void kernel_launch(void* const* d_in, const int* in_sizes, int n_in,
                              void* d_out, int out_size, void* d_ws, size_t ws_size,
                              hipStream_t stream) {
    const float* x  = (const float*)d_in[0];
    const float* bw = (const float*)d_in[2];
    const float* sw = (const float*)d_in[3];
    const float* sc = (const float*)d_in[4];
    float* out = (float*)d_out;

    const int batch = in_sizes[0] / IN_F;   // 8192
    const int n4    = in_sizes[0] / 4;

    unsigned*       mm = (unsigned*)d_ws;
    unsigned short* Wc = (unsigned short*)((char*)d_ws + 512);
    const size_t    wc_bytes = (size_t)OUT_F * KDIM * 2;               // 18.9 MB
    unsigned short* Ac = (unsigned short*)((char*)d_ws + 512 + wc_bytes);
    const size_t    ac_bytes = (size_t)batch * KDIM * 2;               // 151 MB
    const size_t    need = 512 + wc_bytes + ac_bytes;

    hipMemsetAsync(d_ws, 0, 8, stream);
    k_minmax<<<1024, 256, 0, stream>>>(x, mm, n4);

    const int nba = (batch * IN_F) / 256;
    k_prep_all<<<nba + (OUT_F * IN_F) / 256, 256, 0, stream>>>(x, mm, bw, sw, sc, Ac, Wc, nba);

    if (ws_size >= need && batch == 8192) {
        k_gemm5<<<dim3((batch / BM3) * (OUT_F / BN3)), 512, 0, stream>>>(Ac, Wc, out);
    } else if (ws_size >= need && (batch % BM) == 0) {
        k_gemm2<<<dim3((batch / BM) * (OUT_F / BN)), 256, 0, stream>>>(Ac, Wc, out, batch / BM);
    }
}

// Round 8
// 300.289 us; speedup vs baseline: 1.6567x; 1.6567x over previous
//
#include <hip/hip_runtime.h>
#include <hip/hip_bf16.h>

#define IN_F   1024
#define OUT_F  1024
#define NBASIS 8
#define KDIM   (IN_F + IN_F * NBASIS)   // 9216
#define BK 64
#define KT      (KDIM / BK)             // 144

// ---- k_gemm6 geometry ----------------------------------------------------
#define BM3 128
#define BN3 256
#define A_ELEMS (BM3 * BK)              // 8192 shorts (16 KB)
#define B_ELEMS (BN3 * BK)              // 16384 shorts (32 KB)
#define SLOT    (A_ELEMS + B_ELEMS)     // 24576 shorts (48 KB)
#define A_OFF   0
#define B_OFF   A_ELEMS

// ---- fallback geometry ----------------------------------------------------
#define BM 128
#define BN 128

typedef __attribute__((ext_vector_type(8)))  short          bf16x8;
typedef __attribute__((ext_vector_type(8)))  unsigned short u16x8;
typedef __attribute__((ext_vector_type(4)))  float          f32x4;

typedef const __attribute__((address_space(1))) void gas_t;
typedef __attribute__((address_space(3))) void las_t;
#define GLD16(g, l) __builtin_amdgcn_global_load_lds((gas_t*)(g), (las_t*)(l), 16, 0, 0)

// ---- helpers -------------------------------------------------------------
__device__ __forceinline__ unsigned short bfr(float f) {
    unsigned u = __float_as_uint(f);
    unsigned r = (u + 0x7FFFu + ((u >> 16) & 1u)) >> 16;
    return (unsigned short)r;
}
__device__ __forceinline__ float silu_f(float v) { return v / (1.0f + __expf(-v)); }

__device__ __forceinline__ unsigned fkey(float f) {
    unsigned u = __float_as_uint(f);
    return u ^ ((u >> 31) ? 0xFFFFFFFFu : 0x80000000u);
}
__device__ __forceinline__ float fkey_dec(unsigned u) {
    unsigned b = (u >> 31) ? (u ^ 0x80000000u) : ~u;
    return __uint_as_float(b);
}

// spline basis (uniform cubic, closed form — validated rounds 1-5)
__device__ __forceinline__ void spline8(float xv, float xmin, float scale, u16x8* o8p) {
    float xn = (xv - xmin) * scale - 1.0f;
    float u  = (xn + 2.2f) * 2.5f;       // h=0.4, t0=-2.2
    int   iv = (int)floorf(u);
    iv = iv < 3 ? 3 : (iv > 7 ? 7 : iv);
    float tt = u - (float)iv;
    float s1 = 1.0f - tt;
    float t2 = tt * tt, t3 = t2 * tt;
    float n0 = s1 * s1 * s1 * (1.0f / 6.0f);
    float n1 = (3.0f * t3 - 6.0f * t2 + 4.0f) * (1.0f / 6.0f);
    float n2 = (-3.0f * t3 + 3.0f * t2 + 3.0f * tt + 1.0f) * (1.0f / 6.0f);
    float n3 = t3 * (1.0f / 6.0f);
    int j0 = iv - 3;
    u16x8 o8;
    #pragma unroll
    for (int s = 0; s < 8; ++s) {
        int d = s - j0;
        float val = (d == 0) ? n0 : (d == 1) ? n1 : (d == 2) ? n2 : (d == 3) ? n3 : 0.0f;
        o8[s] = bfr(val);
    }
    *o8p = o8;
}

// ---- kernel 1: global min/max of x --------------------------------------
__global__ void k_minmax(const float* __restrict__ x, unsigned* __restrict__ mm, int n4) {
    int tid    = blockIdx.x * blockDim.x + threadIdx.x;
    int stride = gridDim.x * blockDim.x;
    const float4* x4 = (const float4*)x;
    float mx  = -3.402823466e+38f;
    float mxn = -3.402823466e+38f;
    for (int i = tid; i < n4; i += stride) {
        float4 v = x4[i];
        mx  = fmaxf(mx,  fmaxf(fmaxf(v.x, v.y), fmaxf(v.z, v.w)));
        mxn = fmaxf(mxn, -fminf(fminf(v.x, v.y), fminf(v.z, v.w)));
    }
    #pragma unroll
    for (int off = 32; off; off >>= 1) {
        mx  = fmaxf(mx,  __shfl_down(mx,  off));
        mxn = fmaxf(mxn, __shfl_down(mxn, off));
    }
    __shared__ float smx[4], smn[4];
    int lane = threadIdx.x & 63, wid = threadIdx.x >> 6;
    if (lane == 0) { smx[wid] = mx; smn[wid] = mxn; }
    __syncthreads();
    if (threadIdx.x == 0) {
        #pragma unroll
        for (int w = 1; w < 4; ++w) { mx = fmaxf(mx, smx[w]); mxn = fmaxf(mxn, smn[w]); }
        atomicMax(&mm[0], fkey(mx));
        atomicMax(&mm[1], fkey(mxn));
    }
}

// ---- kernel 2: merged prep — build Ac AND Wc in one launch ---------------
__global__ void k_prep_all(const float* __restrict__ x, const unsigned* __restrict__ mm,
                           const float* __restrict__ bw, const float* __restrict__ sw,
                           const float* __restrict__ sc,
                           unsigned short* __restrict__ Ac, unsigned short* __restrict__ Wc,
                           int nba) {
    int bid = blockIdx.x;
    if (bid < nba) {
        int t = bid * 256 + threadIdx.x;
        int row = t >> 10, i = t & 1023;
        const float xmax  = fkey_dec(mm[0]);
        const float xmin  = -fkey_dec(mm[1]);
        const float scale = 2.0f / (xmax - xmin + 1e-8f);
        float xv = x[t];
        size_t rb = (size_t)row * KDIM;
        Ac[rb + i] = bfr(silu_f(xv));
        u16x8 o8;
        spline8(xv, xmin, scale, &o8);
        *(u16x8*)(Ac + rb + IN_F + (size_t)i * 8) = o8;
    } else {
        int t = (bid - nba) * 256 + threadIdx.x;
        int o = t >> 10, i = t & 1023;
        Wc[(size_t)o * KDIM + i] = bfr(bw[t]);
        float s = sc[t];
        const float4* swv = (const float4*)(sw + (size_t)t * 8);
        float4 a = swv[0], b = swv[1];
        u16x8 o8;
        o8[0] = bfr(a.x * s); o8[1] = bfr(a.y * s); o8[2] = bfr(a.z * s); o8[3] = bfr(a.w * s);
        o8[4] = bfr(b.x * s); o8[5] = bfr(b.y * s); o8[6] = bfr(b.z * s); o8[7] = bfr(b.w * s);
        *(u16x8*)(Wc + (size_t)o * KDIM + IN_F + i * 8) = o8;
    }
}

#define MFMA16(a, b, c) __builtin_amdgcn_mfma_f32_16x16x32_bf16((a), (b), (c), 0, 0, 0)

// ---- kernel 3: 4-phase counted-vmcnt GEMM (T2+T3+T4+T5) ------------------
// Round-3 structure (proven 160us, 0 conflicts) with the K-tile split into
// 4 phases of 8 MFMA each, ds_reads and GLDs interleaved per phase.
// BM3=128 x BN3=256, 8 waves (2M x 4N), wave tile 64x64, 16x16x32 MFMA.
// Triple-buffered LDS (144 KB), prefetch 2 tiles, steady-state vmcnt(6).
__global__ __launch_bounds__(512, 2)
void k_gemm6(const unsigned short* __restrict__ Ac, const unsigned short* __restrict__ Wc,
             float* __restrict__ out) {
    __shared__ unsigned short sm[3 * SLOT];   // 147456 B

    const int t    = threadIdx.x;
    const int lane = t & 63, w = t >> 6;
    const int bid  = blockIdx.x;
    const int xcd = bid & 7, s = bid >> 3;
    const int bM  = xcd * 8 + (s & 7);        // [0,64)
    const int bN  = s >> 3;                   // [0,4)

    const int wave_r = w >> 2;                // M-half (64 rows)
    const int wcq    = w & 3;                 // N-quarter (64 cols)
    const int l15  = lane & 15;
    const int ach0 = (lane >> 4) ^ (lane & 7);   // K [0,32) chunk, zero-conflict (r3)
    const int ach1 = ach0 ^ 4;                   // K [32,64)

    // ---- staging source pointers (chunk-XOR pre-swizzled global addrs) ----
    const unsigned short* pa0; const unsigned short* pa1;
    const unsigned short* pb0; const unsigned short* pb1;
    const unsigned short* pb2; const unsigned short* pb3;
    {
        int L, r, c;
        L = (0 * 8 + w) * 64 + lane; r = L >> 3; c = L & 7;
        pa0 = Ac + (size_t)(bM * BM3 + r) * KDIM + (c ^ (r & 7)) * 8;
        L = (1 * 8 + w) * 64 + lane; r = L >> 3; c = L & 7;
        pa1 = Ac + (size_t)(bM * BM3 + r) * KDIM + (c ^ (r & 7)) * 8;
        L = (0 * 8 + w) * 64 + lane; r = L >> 3; c = L & 7;
        pb0 = Wc + (size_t)(bN * BN3 + r) * KDIM + (c ^ (r & 7)) * 8;
        L = (1 * 8 + w) * 64 + lane; r = L >> 3; c = L & 7;
        pb1 = Wc + (size_t)(bN * BN3 + r) * KDIM + (c ^ (r & 7)) * 8;
        L = (2 * 8 + w) * 64 + lane; r = L >> 3; c = L & 7;
        pb2 = Wc + (size_t)(bN * BN3 + r) * KDIM + (c ^ (r & 7)) * 8;
        L = (3 * 8 + w) * 64 + lane; r = L >> 3; c = L & 7;
        pb3 = Wc + (size_t)(bN * BN3 + r) * KDIM + (c ^ (r & 7)) * 8;
    }

    f32x4 acc[4][4] = {};   // [mi][ni]

    // ---- prologue: stage tile 0 -> slot0, tile 1 -> slot1 ----
    GLD16(pa0, &sm[0 * SLOT + A_OFF + (0 * 8 + w) * 512]);
    GLD16(pa1, &sm[0 * SLOT + A_OFF + (1 * 8 + w) * 512]);
    GLD16(pb0, &sm[0 * SLOT + B_OFF + (0 * 8 + w) * 512]);
    GLD16(pb1, &sm[0 * SLOT + B_OFF + (1 * 8 + w) * 512]);
    GLD16(pb2, &sm[0 * SLOT + B_OFF + (2 * 8 + w) * 512]);
    GLD16(pb3, &sm[0 * SLOT + B_OFF + (3 * 8 + w) * 512]);
    pa0 += BK; pa1 += BK; pb0 += BK; pb1 += BK; pb2 += BK; pb3 += BK;
    GLD16(pa0, &sm[1 * SLOT + A_OFF + (0 * 8 + w) * 512]);
    GLD16(pa1, &sm[1 * SLOT + A_OFF + (1 * 8 + w) * 512]);
    GLD16(pb0, &sm[1 * SLOT + B_OFF + (0 * 8 + w) * 512]);
    GLD16(pb1, &sm[1 * SLOT + B_OFF + (1 * 8 + w) * 512]);
    GLD16(pb2, &sm[1 * SLOT + B_OFF + (2 * 8 + w) * 512]);
    GLD16(pb3, &sm[1 * SLOT + B_OFF + (3 * 8 + w) * 512]);
    pa0 += BK; pa1 += BK; pb0 += BK; pb1 += BK; pb2 += BK; pb3 += BK;

    int o0 = 0, o1 = SLOT, o2 = 2 * SLOT;   // slots: tile t, t+1, t+2
    int sk = 2;

    asm volatile("s_waitcnt vmcnt(6)" ::: "memory");   // tile 0 landed
    asm volatile("s_barrier" ::: "memory");

    for (int kt = 0; kt < KT; ++kt) {
        bf16x8 af0[4], af1[4];
        // ===== PHASE 1: A-k0 + B-k0(ni0,1); stage A(t+2); MFMA acc[*][0,1] k0
        {
            #pragma unroll
            for (int mi = 0; mi < 4; ++mi) {
                int r = wave_r * 64 + mi * 16 + l15;
                af0[mi] = *(const bf16x8*)&sm[o0 + A_OFF + r * BK + ach0 * 8];
            }
            bf16x8 bf[2];
            #pragma unroll
            for (int ni = 0; ni < 2; ++ni) {
                int r = wcq * 64 + ni * 16 + l15;
                bf[ni] = *(const bf16x8*)&sm[o0 + B_OFF + r * BK + ach0 * 8];
            }
            GLD16(pa0, &sm[o2 + A_OFF + (0 * 8 + w) * 512]);
            GLD16(pa1, &sm[o2 + A_OFF + (1 * 8 + w) * 512]);
            __builtin_amdgcn_s_barrier();
            __builtin_amdgcn_s_setprio(1);
            #pragma unroll
            for (int ni = 0; ni < 2; ++ni)
                #pragma unroll
                for (int mi = 0; mi < 4; ++mi)
                    acc[mi][ni] = MFMA16(af0[mi], bf[ni], acc[mi][ni]);
            __builtin_amdgcn_s_setprio(0);
            __builtin_amdgcn_s_barrier();
        }
        // ===== PHASE 2: B-k0(ni2,3); stage B0,B1(t+2); MFMA acc[*][2,3] k0
        {
            bf16x8 bf[2];
            #pragma unroll
            for (int ni = 0; ni < 2; ++ni) {
                int r = wcq * 64 + (ni + 2) * 16 + l15;
                bf[ni] = *(const bf16x8*)&sm[o0 + B_OFF + r * BK + ach0 * 8];
            }
            GLD16(pb0, &sm[o2 + B_OFF + (0 * 8 + w) * 512]);
            GLD16(pb1, &sm[o2 + B_OFF + (1 * 8 + w) * 512]);
            __builtin_amdgcn_s_barrier();
            __builtin_amdgcn_s_setprio(1);
            #pragma unroll
            for (int ni = 0; ni < 2; ++ni)
                #pragma unroll
                for (int mi = 0; mi < 4; ++mi)
                    acc[mi][ni + 2] = MFMA16(af0[mi], bf[ni], acc[mi][ni + 2]);
            __builtin_amdgcn_s_setprio(0);
            __builtin_amdgcn_s_barrier();
        }
        // ===== PHASE 3: A-k1 + B-k1(ni0,1); stage B2,B3(t+2); MFMA acc[*][0,1] k1
        {
            #pragma unroll
            for (int mi = 0; mi < 4; ++mi) {
                int r = wave_r * 64 + mi * 16 + l15;
                af1[mi] = *(const bf16x8*)&sm[o0 + A_OFF + r * BK + ach1 * 8];
            }
            bf16x8 bf[2];
            #pragma unroll
            for (int ni = 0; ni < 2; ++ni) {
                int r = wcq * 64 + ni * 16 + l15;
                bf[ni] = *(const bf16x8*)&sm[o0 + B_OFF + r * BK + ach1 * 8];
            }
            GLD16(pb2, &sm[o2 + B_OFF + (2 * 8 + w) * 512]);
            GLD16(pb3, &sm[o2 + B_OFF + (3 * 8 + w) * 512]);
            __builtin_amdgcn_s_barrier();
            __builtin_amdgcn_s_setprio(1);
            #pragma unroll
            for (int ni = 0; ni < 2; ++ni)
                #pragma unroll
                for (int mi = 0; mi < 4; ++mi)
                    acc[mi][ni] = MFMA16(af1[mi], bf[ni], acc[mi][ni]);
            __builtin_amdgcn_s_setprio(0);
            __builtin_amdgcn_s_barrier();
        }
        // ===== PHASE 4: B-k1(ni2,3); MFMA acc[*][2,3] k1; tile boundary
        {
            bf16x8 bf[2];
            #pragma unroll
            for (int ni = 0; ni < 2; ++ni) {
                int r = wcq * 64 + (ni + 2) * 16 + l15;
                bf[ni] = *(const bf16x8*)&sm[o0 + B_OFF + r * BK + ach1 * 8];
            }
            __builtin_amdgcn_s_barrier();
            __builtin_amdgcn_s_setprio(1);
            #pragma unroll
            for (int ni = 0; ni < 2; ++ni)
                #pragma unroll
                for (int mi = 0; mi < 4; ++mi)
                    acc[mi][ni + 2] = MFMA16(af1[mi], bf[ni], acc[mi][ni + 2]);
            __builtin_amdgcn_s_setprio(0);
        }

        // advance stage pointers (wrap past KT: redundant re-stage — safe)
        pa0 += BK; pa1 += BK; pb0 += BK; pb1 += BK; pb2 += BK; pb3 += BK;
        if (++sk == KT) {
            sk = 0;
            pa0 -= KDIM; pa1 -= KDIM; pb0 -= KDIM; pb1 -= KDIM; pb2 -= KDIM; pb3 -= KDIM;
        }

        asm volatile("s_waitcnt vmcnt(6)" ::: "memory");   // tile t+1 landed
        asm volatile("s_barrier" ::: "memory");
        int tmp = o0; o0 = o1; o1 = o2; o2 = tmp;
    }

    // ---- epilogue: C/D layout col=lane&15, row=(lane>>4)*4+reg ----
    #pragma unroll
    for (int mi = 0; mi < 4; ++mi) {
        #pragma unroll
        for (int ni = 0; ni < 4; ++ni) {
            #pragma unroll
            for (int reg = 0; reg < 4; ++reg) {
                int row = bM * BM3 + wave_r * 64 + mi * 16 + (lane >> 4) * 4 + reg;
                int col = bN * BN3 + wcq * 64 + ni * 16 + l15;
                out[(size_t)row * OUT_F + col] = acc[mi][ni][reg];
            }
        }
    }
}

// ---- fallback GEMM (round-2 validated m97 structure, 16x16 MFMA) ---------
__global__ __launch_bounds__(256, 2)
void k_gemm2(const unsigned short* __restrict__ Ac, const unsigned short* __restrict__ Wc,
             float* __restrict__ out, int nmb) {
    __shared__ unsigned short As[BM * BK];
    __shared__ unsigned short Bs[BN * BK];

    const int t = threadIdx.x;
    const int lane = t & 63, w = t >> 6;
    int bid = blockIdx.x;
    int bM = bid >> 3, bN = bid & 7;

    const unsigned short* pa[4];
    const unsigned short* pb[4];
    #pragma unroll
    for (int q = 0; q < 4; ++q) {
        int idx = (q * 4 + w) * 64 + lane;
        int r = idx >> 3, c8 = idx & 7;
        pa[q] = Ac + (size_t)(bM * BM + r) * KDIM + c8 * 8;
        pb[q] = Wc + (size_t)(bN * BN + r) * KDIM + c8 * 8;
    }

    const int wr  = (w >> 1) * 64;
    const int wc2 = (w & 1) * 64;

    f32x4 acc[4][4] = {};

    for (int kt = 0; kt < KT; ++kt) {
        __syncthreads();
        #pragma unroll
        for (int q = 0; q < 4; ++q) {
            GLD16(pa[q], &As[(q * 4 + w) * 512]);
            GLD16(pb[q], &Bs[(q * 4 + w) * 512]);
            pa[q] += BK;
            pb[q] += BK;
        }
        __syncthreads();

        bf16x8 af[4][2];
        #pragma unroll
        for (int mi = 0; mi < 4; ++mi) {
            int row = wr + mi * 16 + (lane & 15);
            #pragma unroll
            for (int ks = 0; ks < 2; ++ks)
                af[mi][ks] = *(const bf16x8*)&As[row * BK + ks * 32 + (lane >> 4) * 8];
        }
        #pragma unroll
        for (int ni = 0; ni < 4; ++ni) {
            int col = wc2 + ni * 16 + (lane & 15);
            bf16x8 b0 = *(const bf16x8*)&Bs[col * BK + (lane >> 4) * 8];
            bf16x8 b1 = *(const bf16x8*)&Bs[col * BK + 32 + (lane >> 4) * 8];
            #pragma unroll
            for (int mi = 0; mi < 4; ++mi) {
                acc[mi][ni] = MFMA16(af[mi][0], b0, acc[mi][ni]);
                acc[mi][ni] = MFMA16(af[mi][1], b1, acc[mi][ni]);
            }
        }
    }

    #pragma unroll
    for (int mi = 0; mi < 4; ++mi) {
        #pragma unroll
        for (int ni = 0; ni < 4; ++ni) {
            #pragma unroll
            for (int reg = 0; reg < 4; ++reg) {
                int row = wr + mi * 16 + (lane >> 4) * 4 + reg;
                int col = wc2 + ni * 16 + (lane & 15);
                out[(size_t)(bM * BM + row) * OUT_F + bN * BN + col] = acc[mi][ni][reg];
            }
        }
    }
}

// ---- launch --------------------------------------------------------------
extern "C" void kernel_launch(void* const* d_in, const int* in_sizes, int n_in,
                              void* d_out, int out_size, void* d_ws, size_t ws_size,
                              hipStream_t stream) {
    const float* x  = (const float*)d_in[0];
    const float* bw = (const float*)d_in[2];
    const float* sw = (const float*)d_in[3];
    const float* sc = (const float*)d_in[4];
    float* out = (float*)d_out;

    const int batch = in_sizes[0] / IN_F;   // 8192
    const int n4    = in_sizes[0] / 4;

    unsigned*       mm = (unsigned*)d_ws;
    unsigned short* Wc = (unsigned short*)((char*)d_ws + 512);
    const size_t    wc_bytes = (size_t)OUT_F * KDIM * 2;               // 18.9 MB
    unsigned short* Ac = (unsigned short*)((char*)d_ws + 512 + wc_bytes);
    const size_t    ac_bytes = (size_t)batch * KDIM * 2;               // 151 MB
    const size_t    need = 512 + wc_bytes + ac_bytes;

    hipMemsetAsync(d_ws, 0, 8, stream);
    k_minmax<<<1024, 256, 0, stream>>>(x, mm, n4);

    const int nba = (batch * IN_F) / 256;
    k_prep_all<<<nba + (OUT_F * IN_F) / 256, 256, 0, stream>>>(x, mm, bw, sw, sc, Ac, Wc, nba);

    if (ws_size >= need && batch == 8192) {
        k_gemm6<<<dim3((batch / BM3) * (OUT_F / BN3)), 512, 0, stream>>>(Ac, Wc, out);
    } else if (ws_size >= need && (batch % BM) == 0) {
        k_gemm2<<<dim3((batch / BM) * (OUT_F / BN)), 256, 0, stream>>>(Ac, Wc, out, batch / BM);
    }
}